// Round 2
// baseline (607.308 us; speedup 1.0000x reference)
//
#include <hip/hip_runtime.h>
#include <hip/hip_bf16.h>
#include <stdint.h>

// Problem constants (fixed by the reference)
#define M_DIM 8192      // 4 * 2048
#define K_DIM 4096      // INPUT_DIM
#define N_DIM 4096      // OUTPUT_DIM
#define NGROUPS 2097152 // INDEX_LENGTH

typedef __attribute__((ext_vector_type(8))) __bf16 bf16x8;
typedef __attribute__((ext_vector_type(4))) float f32x4;
typedef __attribute__((ext_vector_type(8))) unsigned short ushort8;

// fp32 -> bf16 round-to-nearest-even (bit trick; inputs are normal floats)
__device__ __forceinline__ unsigned short f2bf(float f) {
    union { float f; uint32_t u; } v; v.f = f;
    return (unsigned short)((v.u + 0x7fffu + ((v.u >> 16) & 1u)) >> 16);
}

// ---------------- kernel 1: x fp32 -> bf16 ----------------
__global__ __launch_bounds__(256) void convert_x_kernel(const float* __restrict__ x,
                                                        unsigned short* __restrict__ xb,
                                                        int n8) {
    int i = blockIdx.x * blockDim.x + threadIdx.x;
    int stride = gridDim.x * blockDim.x;
    for (; i < n8; i += stride) {
        const float4* p = (const float4*)(x + (size_t)i * 8);
        float4 a = p[0], b = p[1];
        ushort8 o;
        o[0] = f2bf(a.x); o[1] = f2bf(a.y); o[2] = f2bf(a.z); o[3] = f2bf(a.w);
        o[4] = f2bf(b.x); o[5] = f2bf(b.y); o[6] = f2bf(b.z); o[7] = f2bf(b.w);
        *(ushort8*)(xb + (size_t)i * 8) = o;
    }
}

// ---------------- kernel 2: gather + transpose weight -> bf16 Wt[n][k] ----------------
// weight flat index f = k*N + n; group g = f/8 covers 8 consecutive n at fixed k.
// Block handles tile k in [k0,k0+64), n in [n0,n0+64); LDS transpose for coalesced output.
__global__ __launch_bounds__(256) void gather_kernel(const float* __restrict__ bank,
                                                     const int* __restrict__ index,
                                                     unsigned short* __restrict__ Wt) {
    __shared__ unsigned short lds[64][68]; // [n_local][k_local], pad to 68 to spread banks
    const int n0 = blockIdx.x * 64;
    const int k0 = blockIdx.y * 64;
    const int t = threadIdx.x;
    const int kl = t >> 2;   // 0..63
    const int jj = t & 3;

    #pragma unroll
    for (int h = 0; h < 2; h++) {
        int j = jj + h * 4;                              // 0..7 : group within k-row
        int g = (k0 + kl) * (N_DIM / 8) + (n0 >> 3) + j; // group id
        int idx = index[g];
        const float4* vb = (const float4*)(bank + (size_t)idx * 8);
        float4 a = vb[0], b = vb[1];
        int nl = j * 8;
        lds[nl + 0][kl] = f2bf(a.x);
        lds[nl + 1][kl] = f2bf(a.y);
        lds[nl + 2][kl] = f2bf(a.z);
        lds[nl + 3][kl] = f2bf(a.w);
        lds[nl + 4][kl] = f2bf(b.x);
        lds[nl + 5][kl] = f2bf(b.y);
        lds[nl + 6][kl] = f2bf(b.z);
        lds[nl + 7][kl] = f2bf(b.w);
    }
    __syncthreads();
    // write out: Wt[n0+r][k0 + c*8 .. +7], coalesced 16B stores
    const int r = t >> 2;
    #pragma unroll
    for (int h = 0; h < 2; h++) {
        int c = (t & 3) + h * 4; // 0..7
        ushort8 v;
        #pragma unroll
        for (int i = 0; i < 8; i++) v[i] = lds[r][c * 8 + i];
        *(ushort8*)(Wt + (size_t)(n0 + r) * K_DIM + k0 + c * 8) = v;
    }
}

// ---------------- kernel 3: bf16 GEMM, m97 structure ----------------
// C[M][N] = A[M][K] * Wt[N][K]^T + bias.  BM=BN=128, BK=32, 4 waves (2x2), 4x4 MFMA frags/wave.
#define GLDS(g, l) __builtin_amdgcn_global_load_lds(                                   \
    (const __attribute__((address_space(1))) void*)(g),                                \
    (__attribute__((address_space(3))) void*)(l), 16, 0, 0)

__global__ __launch_bounds__(256) void gemm_kernel(const unsigned short* __restrict__ A,
                                                   const unsigned short* __restrict__ Bt,
                                                   const float* __restrict__ bias,
                                                   float* __restrict__ C) {
    __shared__ unsigned short As[128][32];
    __shared__ unsigned short Bs[128][32];

    const int tid = threadIdx.x;
    const int lane = tid & 63;
    const int wave = tid >> 6;      // 0..3
    const int wm = wave >> 1;       // 0..1
    const int wn = wave & 1;        // 0..1
    const int m0 = blockIdx.y * 128;
    const int n0 = blockIdx.x * 128;

    // staging: chunk c covers LDS rows [16c,16c+16); wave handles chunks {wave, wave+4}.
    // lane l -> row 16c + (l>>2), elems (l&3)*8 .. +7 (one 16B global_load_lds per lane)
    const int srow = lane >> 2;
    const int scol = (lane & 3) * 8;
    const unsigned short* gA0 = A + (size_t)(m0 + wave * 16 + srow) * K_DIM + scol;
    const unsigned short* gA1 = A + (size_t)(m0 + (wave + 4) * 16 + srow) * K_DIM + scol;
    const unsigned short* gB0 = Bt + (size_t)(n0 + wave * 16 + srow) * K_DIM + scol;
    const unsigned short* gB1 = Bt + (size_t)(n0 + (wave + 4) * 16 + srow) * K_DIM + scol;
    unsigned short* lA0 = &As[wave * 16][0];
    unsigned short* lA1 = &As[(wave + 4) * 16][0];
    unsigned short* lB0 = &Bs[wave * 16][0];
    unsigned short* lB1 = &Bs[(wave + 4) * 16][0];

    f32x4 acc[4][4];
    #pragma unroll
    for (int i = 0; i < 4; i++)
        #pragma unroll
        for (int j = 0; j < 4; j++)
            acc[i][j] = (f32x4){0.f, 0.f, 0.f, 0.f};

    const int ra = wm * 64 + (lane & 15); // A fragment row within tile
    const int rb = wn * 64 + (lane & 15); // B fragment row (n) within tile
    const int ks = (lane >> 4) * 8;       // k sub-offset within BK

    for (int k0 = 0; k0 < K_DIM; k0 += 32) {
        GLDS(gA0 + k0, lA0);
        GLDS(gA1 + k0, lA1);
        GLDS(gB0 + k0, lB0);
        GLDS(gB1 + k0, lB1);
        __syncthreads(); // drains vmcnt (global_load_lds) + lgkmcnt

        bf16x8 af[4], bf[4];
        #pragma unroll
        for (int i = 0; i < 4; i++) af[i] = *(const bf16x8*)&As[ra + i * 16][ks];
        #pragma unroll
        for (int i = 0; i < 4; i++) bf[i] = *(const bf16x8*)&Bs[rb + i * 16][ks];

        #pragma unroll
        for (int mi = 0; mi < 4; mi++)
            #pragma unroll
            for (int ni = 0; ni < 4; ni++)
                acc[mi][ni] = __builtin_amdgcn_mfma_f32_16x16x32_bf16(
                    af[mi], bf[ni], acc[mi][ni], 0, 0, 0);

        __syncthreads(); // protect LDS from next iteration's staging
    }

    // epilogue: D[row = 4*(lane>>4)+r][col = lane&15] per 16x16 fragment
    const int orow_base = m0 + wm * 64 + 4 * (lane >> 4);
    const int ocol_base = n0 + wn * 64 + (lane & 15);
    #pragma unroll
    for (int ni = 0; ni < 4; ni++) {
        int col = ocol_base + ni * 16;
        float bv = bias[col];
        #pragma unroll
        for (int mi = 0; mi < 4; mi++) {
            #pragma unroll
            for (int r = 0; r < 4; r++) {
                int row = orow_base + mi * 16 + r;
                C[(size_t)row * N_DIM + col] = acc[mi][ni][r] + bv;
            }
        }
    }
}

extern "C" void kernel_launch(void* const* d_in, const int* in_sizes, int n_in,
                              void* d_out, int out_size, void* d_ws, size_t ws_size,
                              hipStream_t stream) {
    const float* x = (const float*)d_in[0];
    const float* bank = (const float*)d_in[1];
    const int* index = (const int*)d_in[2];
    const float* bias = (const float*)d_in[3];
    float* out = (float*)d_out;

    // workspace: Abf (M*K bf16 = 64MB) | Wt (N*K bf16 = 32MB)
    const size_t need = (size_t)M_DIM * K_DIM * 2 + (size_t)N_DIM * K_DIM * 2;
    if (ws_size < need) return; // insufficient scratch -> fail loudly via absmax
    unsigned short* Abf = (unsigned short*)d_ws;
    unsigned short* Wt = Abf + (size_t)M_DIM * K_DIM;

    convert_x_kernel<<<4096, 256, 0, stream>>>(x, Abf, M_DIM * K_DIM / 8);
    gather_kernel<<<dim3(N_DIM / 64, K_DIM / 64), 256, 0, stream>>>(bank, index, Wt);
    gemm_kernel<<<dim3(N_DIM / 128, M_DIM / 128), 256, 0, stream>>>(Abf, Wt, bias, out);
}